// Round 4
// baseline (614.413 us; speedup 1.0000x reference)
//
#include <hip/hip_runtime.h>
#include <hip/hip_bf16.h>

typedef __bf16 bf16_t;
typedef __bf16 bf16x8 __attribute__((ext_vector_type(8)));
typedef float  f32x4  __attribute__((ext_vector_type(4)));

#define MFMA_BF16 __builtin_amdgcn_mfma_f32_16x16x32_bf16
#define NEG_BIG  (-3.0e38f)

// ---------------------------------------------------------------------------
// fp32 -> bf16 conversion, 8 elements/thread. n must be divisible by 2048.
// ---------------------------------------------------------------------------
__global__ __launch_bounds__(256) void cvt_f32_bf16(
    const float* __restrict__ in, bf16_t* __restrict__ out)
{
    size_t i = ((size_t)blockIdx.x * 256 + threadIdx.x) * 8;
    f32x4 a = *(const f32x4*)&in[i];
    f32x4 b = *(const f32x4*)&in[i + 4];
    bf16x8 o;
    o[0] = (bf16_t)a[0]; o[1] = (bf16_t)a[1]; o[2] = (bf16_t)a[2]; o[3] = (bf16_t)a[3];
    o[4] = (bf16_t)b[0]; o[5] = (bf16_t)b[1]; o[6] = (bf16_t)b[2]; o[7] = (bf16_t)b[3];
    *(bf16x8*)&out[i] = o;
}

// ---------------------------------------------------------------------------
// LoRA first stage: out[m][r] = sum_k X[m][k] * A[r][k]   (X: [M,1024] bf16,
// A: [8,1024] fp32, out: [M,8] fp32). One wave per row m. M = 8192.
// ---------------------------------------------------------------------------
__global__ __launch_bounds__(256) void lora_xa_kernel(
    const bf16_t* __restrict__ X, const float* __restrict__ A,
    float* __restrict__ out)
{
    const int lane = threadIdx.x & 63;
    const int w    = threadIdx.x >> 6;
    const int m    = blockIdx.x * 4 + w;
    const bf16_t* xp = X + (size_t)m * 1024;

    float acc[8];
#pragma unroll
    for (int r = 0; r < 8; r++) acc[r] = 0.f;

#pragma unroll 4
    for (int ci = 0; ci < 16; ci++) {
        int k = ci * 64 + lane;
        float xv = (float)xp[k];
#pragma unroll
        for (int r = 0; r < 8; r++) acc[r] += xv * A[r * 1024 + k];
    }
#pragma unroll
    for (int r = 0; r < 8; r++) {
        float v = acc[r];
        v += __shfl_xor(v, 1);  v += __shfl_xor(v, 2);  v += __shfl_xor(v, 4);
        v += __shfl_xor(v, 8);  v += __shfl_xor(v, 16); v += __shfl_xor(v, 32);
        if (lane == 0) out[m * 8 + r] = v;
    }
}

// ---------------------------------------------------------------------------
// GEMM: C[m][n] = sum_k A[m][k]*W[n][k] + bias[n] + 2*sum_r xA[m][r]*LB[n][r]
// A: [M,K] bf16 row-major (row-local M = grid.y*128), W: [N,K] bf16 row-major
// (B^T layout). bias: fp32 [N], xA: fp32 [M,8], LB: fp32 [N,8].
// Output: if Cf != nullptr -> fp32 [M,1024] (proj path, seg 0 only);
// else bf16 routed to C0/C1/C2 by 1024-column segment (block-uniform).
// 128x128 tile, BK=64, 4 waves (2x2), each wave 64x64 via 4x4 MFMA 16x16x32.
// LDS stride 72: 16B-aligned rows, bank rotation 4/row (<=2-way, free).
// ---------------------------------------------------------------------------
__global__ __launch_bounds__(256) void gemm_bias_lora(
    const bf16_t* __restrict__ A, const bf16_t* __restrict__ W,
    const float* __restrict__ bias, const float* __restrict__ xA,
    const float* __restrict__ LB,
    bf16_t* __restrict__ C0, bf16_t* __restrict__ C1, bf16_t* __restrict__ C2,
    float* __restrict__ Cf, int K)
{
    __shared__ __align__(16) bf16_t As[128 * 72];
    __shared__ __align__(16) bf16_t Bs[128 * 72];

    const int t    = threadIdx.x;
    const int lane = t & 63;
    const int w    = t >> 6;
    const int wm   = (w >> 1) * 64;
    const int wn   = (w & 1) * 64;
    const int c    = lane & 15;
    const int g    = lane >> 4;
    const int tile_m = blockIdx.y * 128;
    const int tile_n = blockIdx.x * 128;

    const int seg    = tile_n >> 10;
    const int tn_loc = tile_n & 1023;
    bf16_t* __restrict__ Cout = (seg == 0) ? C0 : (seg == 1) ? C1 : C2;

    const int srow = t >> 3;             // 0..31
    const int scol = (t & 7) * 8;        // 0..56 step 8

    f32x4 acc[4][4];
#pragma unroll
    for (int i = 0; i < 4; i++)
#pragma unroll
        for (int j = 0; j < 4; j++) {
            f32x4 z = {0.f, 0.f, 0.f, 0.f};
            acc[i][j] = z;
        }

    for (int k0 = 0; k0 < K; k0 += 64) {
#pragma unroll
        for (int i = 0; i < 4; i++) {
            int r = srow + i * 32;
            *(bf16x8*)&As[r * 72 + scol] =
                *(const bf16x8*)&A[(size_t)(tile_m + r) * K + k0 + scol];
            *(bf16x8*)&Bs[r * 72 + scol] =
                *(const bf16x8*)&W[(size_t)(tile_n + r) * K + k0 + scol];
        }
        __syncthreads();

#pragma unroll
        for (int kk = 0; kk < 2; kk++) {
            bf16x8 af[4], bfr[4];
#pragma unroll
            for (int i = 0; i < 4; i++)
                af[i] = *(const bf16x8*)&As[(wm + i * 16 + c) * 72 + kk * 32 + g * 8];
#pragma unroll
            for (int j = 0; j < 4; j++)
                bfr[j] = *(const bf16x8*)&Bs[(wn + j * 16 + c) * 72 + kk * 32 + g * 8];
#pragma unroll
            for (int i = 0; i < 4; i++)
#pragma unroll
                for (int j = 0; j < 4; j++)
                    acc[i][j] = MFMA_BF16(af[i], bfr[j], acc[i][j], 0, 0, 0);
        }
        __syncthreads();
    }

    float biasf[4];
    float lbv[4][8];
#pragma unroll
    for (int j = 0; j < 4; j++) {
        int col = tile_n + wn + j * 16 + c;           // global col
        biasf[j] = bias[col];
        f32x4 lb0 = *(const f32x4*)&LB[(size_t)col * 8];
        f32x4 lb1 = *(const f32x4*)&LB[(size_t)col * 8 + 4];
#pragma unroll
        for (int r = 0; r < 4; r++) { lbv[j][r] = lb0[r]; lbv[j][r + 4] = lb1[r]; }
    }
#pragma unroll
    for (int i = 0; i < 4; i++) {
#pragma unroll
        for (int rg = 0; rg < 4; rg++) {
            int row = tile_m + wm + i * 16 + g * 4 + rg;   // row-local
            f32x4 xa0 = *(const f32x4*)&xA[(size_t)row * 8];
            f32x4 xa1 = *(const f32x4*)&xA[(size_t)row * 8 + 4];
#pragma unroll
            for (int j = 0; j < 4; j++) {
                float lora = xa0[0] * lbv[j][0] + xa0[1] * lbv[j][1] +
                             xa0[2] * lbv[j][2] + xa0[3] * lbv[j][3] +
                             xa1[0] * lbv[j][4] + xa1[1] * lbv[j][5] +
                             xa1[2] * lbv[j][6] + xa1[3] * lbv[j][7];
                float v = acc[i][j][rg] + biasf[j] + 2.0f * lora;
                int lcol = tn_loc + wn + j * 16 + c;
                if (Cf) Cf[(size_t)row * 1024 + lcol] = v;
                else    Cout[(size_t)row * 1024 + lcol] = (bf16_t)v;
            }
        }
    }
}

// ---------------------------------------------------------------------------
// Causal flash attention, ONE BATCH (2048 rows). Q/K/V: [2048,1024] bf16
// (head h at cols h*64). Output written IN PLACE into Q (each block reads its
// Q fragment first; blocks touch disjoint (row, head-col) regions). Block =
// (qb, h), 4 waves x 16 q-rows, KV tiles of 64, scale = 0.125.
// No +-inf: NEG_BIG sentinel (fast-math-safe).
// ---------------------------------------------------------------------------
__global__ __launch_bounds__(256) void attn_kernel(
    bf16_t* __restrict__ Q, const bf16_t* __restrict__ Kg,
    const bf16_t* __restrict__ Vg)
{
    __shared__ __align__(16) bf16_t Ks[64 * 72];       // K[kv][d]
    __shared__ __align__(16) bf16_t Vt[64 * 72];       // V^T[d][kv]
    __shared__ __align__(16) bf16_t Ps[4 * 16 * 72];   // per-wave P[q][kv]

    const int t    = threadIdx.x;
    const int lane = t & 63;
    const int w    = t >> 6;
    const int c    = lane & 15;
    const int g    = lane >> 4;
    const int qb = blockIdx.x, h = blockIdx.y;
    const int q0 = qb * 64;

    bf16x8 qf[2];
    {
        int qrow = q0 + w * 16 + c;
        const bf16_t* qp = Q + (size_t)qrow * 1024 + h * 64;
        qf[0] = *(const bf16x8*)&qp[g * 8];
        qf[1] = *(const bf16x8*)&qp[32 + g * 8];
    }

    f32x4 acc_o[4];
#pragma unroll
    for (int jd = 0; jd < 4; jd++) {
        f32x4 z = {0.f, 0.f, 0.f, 0.f};
        acc_o[jd] = z;
    }
    float m_run[4], l_run[4];
#pragma unroll
    for (int r = 0; r < 4; r++) { m_run[r] = NEG_BIG; l_run[r] = 0.f; }

    const int sr = t >> 2;           // staging kv row 0..63
    const int sc = (t & 3) * 16;     // staging d col {0,16,32,48}

    for (int kt = 0; kt <= qb; kt++) {
        {
            const bf16_t* kp = Kg + (size_t)(kt * 64 + sr) * 1024 + h * 64 + sc;
            *(bf16x8*)&Ks[sr * 72 + sc]     = *(const bf16x8*)&kp[0];
            *(bf16x8*)&Ks[sr * 72 + sc + 8] = *(const bf16x8*)&kp[8];
            const bf16_t* vp = Vg + (size_t)(kt * 64 + sr) * 1024 + h * 64 + sc;
            bf16x8 v0 = *(const bf16x8*)&vp[0];
            bf16x8 v1 = *(const bf16x8*)&vp[8];
#pragma unroll
            for (int e = 0; e < 8; e++) Vt[(sc + e) * 72 + sr] = v0[e];
#pragma unroll
            for (int e = 0; e < 8; e++) Vt[(sc + 8 + e) * 72 + sr] = v1[e];
        }
        __syncthreads();

        f32x4 s[4];
#pragma unroll
        for (int j = 0; j < 4; j++) {
            f32x4 z = {0.f, 0.f, 0.f, 0.f};
            s[j] = z;
        }
#pragma unroll
        for (int kk = 0; kk < 2; kk++) {
            bf16x8 kf[4];
#pragma unroll
            for (int j = 0; j < 4; j++)
                kf[j] = *(const bf16x8*)&Ks[(j * 16 + c) * 72 + kk * 32 + g * 8];
#pragma unroll
            for (int j = 0; j < 4; j++)
                s[j] = MFMA_BF16(qf[kk], kf[j], s[j], 0, 0, 0);
        }

        float sv[4][4];
#pragma unroll
        for (int j = 0; j < 4; j++)
#pragma unroll
            for (int r = 0; r < 4; r++) sv[j][r] = s[j][r] * 0.125f;

        if (kt == qb) {   // diagonal block: causal mask
#pragma unroll
            for (int j = 0; j < 4; j++) {
                int kv = j * 16 + c;
#pragma unroll
                for (int r = 0; r < 4; r++) {
                    int q = w * 16 + g * 4 + r;
                    if (kv > q) sv[j][r] = NEG_BIG;
                }
            }
        }

        float alpha[4];
#pragma unroll
        for (int r = 0; r < 4; r++) {
            float mx = fmaxf(fmaxf(sv[0][r], sv[1][r]), fmaxf(sv[2][r], sv[3][r]));
            mx = fmaxf(mx, __shfl_xor(mx, 1));
            mx = fmaxf(mx, __shfl_xor(mx, 2));
            mx = fmaxf(mx, __shfl_xor(mx, 4));
            mx = fmaxf(mx, __shfl_xor(mx, 8));
            float mnew = fmaxf(m_run[r], mx);
            alpha[r] = __expf(m_run[r] - mnew);
            m_run[r] = mnew;
        }
        float pv[4][4];
#pragma unroll
        for (int j = 0; j < 4; j++)
#pragma unroll
            for (int r = 0; r < 4; r++) pv[j][r] = __expf(sv[j][r] - m_run[r]);
#pragma unroll
        for (int r = 0; r < 4; r++) {
            float sm = pv[0][r] + pv[1][r] + pv[2][r] + pv[3][r];
            sm += __shfl_xor(sm, 1);
            sm += __shfl_xor(sm, 2);
            sm += __shfl_xor(sm, 4);
            sm += __shfl_xor(sm, 8);
            l_run[r] = l_run[r] * alpha[r] + sm;
        }

        bf16_t* Pw = &Ps[w * 16 * 72];
#pragma unroll
        for (int j = 0; j < 4; j++)
#pragma unroll
            for (int r = 0; r < 4; r++)
                Pw[(g * 4 + r) * 72 + j * 16 + c] = (bf16_t)pv[j][r];

#pragma unroll
        for (int jd = 0; jd < 4; jd++)
#pragma unroll
            for (int r = 0; r < 4; r++) acc_o[jd][r] *= alpha[r];

        __syncthreads();

#pragma unroll
        for (int kkv = 0; kkv < 2; kkv++) {
            bf16x8 pf = *(const bf16x8*)&Pw[c * 72 + kkv * 32 + g * 8];
#pragma unroll
            for (int jd = 0; jd < 4; jd++) {
                bf16x8 vf = *(const bf16x8*)&Vt[(jd * 16 + c) * 72 + kkv * 32 + g * 8];
                acc_o[jd] = MFMA_BF16(pf, vf, acc_o[jd], 0, 0, 0);
            }
        }
        __syncthreads();
    }

#pragma unroll
    for (int jd = 0; jd < 4; jd++) {
#pragma unroll
        for (int r = 0; r < 4; r++) {
            int qrow = q0 + w * 16 + g * 4 + r;
            float v = acc_o[jd][r] / l_run[r];
            Q[(size_t)qrow * 1024 + h * 64 + jd * 16 + c] = (bf16_t)v;
        }
    }
}

// ---------------------------------------------------------------------------
extern "C" void kernel_launch(void* const* d_in, const int* in_sizes, int n_in,
                              void* d_out, int out_size, void* d_ws, size_t ws_size,
                              hipStream_t stream) {
    const float* x     = (const float*)d_in[0];   // [4,2048,1024] fp32
    const float* Wqkv  = (const float*)d_in[1];   // [3072,1024]
    const float* bqkv  = (const float*)d_in[2];   // [3072]
    const float* Aqkv  = (const float*)d_in[3];   // [8,1024]
    const float* Bqkv  = (const float*)d_in[4];   // [3072,8]
    const float* Wproj = (const float*)d_in[5];   // [1024,1024]
    const float* bproj = (const float*)d_in[6];   // [1024]
    const float* Aproj = (const float*)d_in[7];   // [8,1024]
    const float* Bproj = (const float*)d_in[8];   // [1024,8]
    float* out = (float*)d_out;                   // [4,2048,1024] fp32

    // workspace map (total 48.5 MiB):
    //   [0,     256K) : xa1 fp32 [8192*8]
    //   [256K,  512K) : xa2 fp32 [8192*8]
    //   [512K, 16.5M) : x16    bf16 [8192*1024]
    //   [16.5M,22.5M) : Wqkv16 bf16 [3072*1024]
    //   [22.5M,24.5M) : Wproj16 bf16 [1024*1024]
    //   [24.5M,40.5M) : Qfull  bf16 [8192*1024]  (attn output in place)
    //   [40.5M,44.5M) : Kb     bf16 [2048*1024]  (per-batch)
    //   [44.5M,48.5M) : Vb     bf16 [2048*1024]  (per-batch)
    char* ws = (char*)d_ws;
    float*  xa1    = (float*)ws;
    float*  xa2    = (float*)(ws + 262144);
    bf16_t* x16    = (bf16_t*)(ws + 524288);
    bf16_t* Wqkv16 = x16 + (size_t)8192 * 1024;
    bf16_t* Wproj16= Wqkv16 + (size_t)3072 * 1024;
    bf16_t* Qfull  = Wproj16 + (size_t)1024 * 1024;
    bf16_t* Kb     = Qfull + (size_t)8192 * 1024;
    bf16_t* Vb     = Kb + (size_t)2048 * 1024;

    // 0) convert inputs to bf16
    cvt_f32_bf16<<<4096, 256, 0, stream>>>(x, x16);        // 8388608 elems
    cvt_f32_bf16<<<1536, 256, 0, stream>>>(Wqkv, Wqkv16);  // 3145728
    cvt_f32_bf16<<< 512, 256, 0, stream>>>(Wproj, Wproj16);// 1048576

    // 1) xA for QKV LoRA (all 8192 rows)
    lora_xa_kernel<<<2048, 256, 0, stream>>>(x16, Aqkv, xa1);

    // 2) per batch: QKV GEMM (Q -> Qfull slice, K/V -> ws) then attention
    for (int b = 0; b < 4; b++) {
        const bf16_t* xb = x16 + (size_t)b * 2048 * 1024;
        bf16_t* Qb = Qfull + (size_t)b * 2048 * 1024;
        gemm_bias_lora<<<dim3(24, 16), 256, 0, stream>>>(
            xb, Wqkv16, bqkv, xa1 + (size_t)b * 2048 * 8, Bqkv,
            Qb, Kb, Vb, nullptr, 1024);
        attn_kernel<<<dim3(32, 16), 256, 0, stream>>>(Qb, Kb, Vb);
    }

    // 3) xA for proj LoRA (reads attn output in Qfull)
    lora_xa_kernel<<<2048, 256, 0, stream>>>(Qfull, Aproj, xa2);

    // 4) proj GEMM: all 8192 rows at once, fp32 output -> d_out
    gemm_bias_lora<<<dim3(8, 64), 256, 0, stream>>>(
        Qfull, Wproj16, bproj, xa2, Bproj,
        nullptr, nullptr, nullptr, out, 1024);
}

// Round 5
// 526.434 us; speedup vs baseline: 1.1671x; 1.1671x over previous
//
#include <hip/hip_runtime.h>
#include <hip/hip_bf16.h>

typedef __bf16 bf16_t;
typedef __bf16 bf16x8 __attribute__((ext_vector_type(8)));
typedef float  f32x4  __attribute__((ext_vector_type(4)));

#define MFMA_BF16 __builtin_amdgcn_mfma_f32_16x16x32_bf16
#define NEG_BIG  (-3.0e38f)

// load 8 contiguous elements as bf16x8, converting if source is fp32
__device__ inline bf16x8 ld8(const bf16_t* p) { return *(const bf16x8*)p; }
__device__ inline bf16x8 ld8(const float* p) {
    f32x4 a = *(const f32x4*)p;
    f32x4 b = *(const f32x4*)(p + 4);
    bf16x8 o;
    o[0] = (bf16_t)a[0]; o[1] = (bf16_t)a[1]; o[2] = (bf16_t)a[2]; o[3] = (bf16_t)a[3];
    o[4] = (bf16_t)b[0]; o[5] = (bf16_t)b[1]; o[6] = (bf16_t)b[2]; o[7] = (bf16_t)b[3];
    return o;
}

// ---------------------------------------------------------------------------
// LoRA first stage: out[m][r] = sum_k X[m][k] * A[r][k]
// X: [M,1024] (fp32 or bf16), A: [8,1024] fp32, out: [M,8] fp32. Wave/row.
// ---------------------------------------------------------------------------
template <typename TX>
__global__ __launch_bounds__(256) void lora_xa_kernel(
    const TX* __restrict__ X, const float* __restrict__ A,
    float* __restrict__ out)
{
    const int lane = threadIdx.x & 63;
    const int w    = threadIdx.x >> 6;
    const int m    = blockIdx.x * 4 + w;
    const TX* xp = X + (size_t)m * 1024;

    float acc[8];
#pragma unroll
    for (int r = 0; r < 8; r++) acc[r] = 0.f;

#pragma unroll 4
    for (int ci = 0; ci < 16; ci++) {
        int k = ci * 64 + lane;
        float xv = (float)xp[k];
#pragma unroll
        for (int r = 0; r < 8; r++) acc[r] += xv * A[r * 1024 + k];
    }
#pragma unroll
    for (int r = 0; r < 8; r++) {
        float v = acc[r];
        v += __shfl_xor(v, 1);  v += __shfl_xor(v, 2);  v += __shfl_xor(v, 4);
        v += __shfl_xor(v, 8);  v += __shfl_xor(v, 16); v += __shfl_xor(v, 32);
        if (lane == 0) out[m * 8 + r] = v;
    }
}

// ---------------------------------------------------------------------------
// GEMM: C[m][n] = sum_k A[m][k]*W[n][k] + bias[n] + 2*sum_r xA[m][r]*LB[n][r]
// A: [M,K] row-major (fp32 or bf16 — converted to bf16 during staging),
// W: [N,K] row-major (fp32 or bf16, B^T layout). bias/xA/LB fp32.
// Output: Cf!=nullptr -> fp32 [M,1024]; else bf16 routed C0/C1/C2 by segment.
// 128x128 tile, BK=64, 4 waves (2x2), 4x4 MFMA 16x16x32 per wave.
// LDS stride 72: 16B-aligned rows, bank rotation 4/row.
// ---------------------------------------------------------------------------
template <typename TA, typename TW>
__global__ __launch_bounds__(256) void gemm_bias_lora(
    const TA* __restrict__ A, const TW* __restrict__ W,
    const float* __restrict__ bias, const float* __restrict__ xA,
    const float* __restrict__ LB,
    bf16_t* __restrict__ C0, bf16_t* __restrict__ C1, bf16_t* __restrict__ C2,
    float* __restrict__ Cf, int K)
{
    __shared__ __align__(16) bf16_t As[128 * 72];
    __shared__ __align__(16) bf16_t Bs[128 * 72];

    const int t    = threadIdx.x;
    const int lane = t & 63;
    const int w    = t >> 6;
    const int wm   = (w >> 1) * 64;
    const int wn   = (w & 1) * 64;
    const int c    = lane & 15;
    const int g    = lane >> 4;
    const int tile_m = blockIdx.y * 128;
    const int tile_n = blockIdx.x * 128;

    const int seg    = tile_n >> 10;
    const int tn_loc = tile_n & 1023;
    bf16_t* __restrict__ Cout = (seg == 0) ? C0 : (seg == 1) ? C1 : C2;

    const int srow = t >> 3;             // 0..31
    const int scol = (t & 7) * 8;        // 0..56 step 8

    f32x4 acc[4][4];
#pragma unroll
    for (int i = 0; i < 4; i++)
#pragma unroll
        for (int j = 0; j < 4; j++) {
            f32x4 z = {0.f, 0.f, 0.f, 0.f};
            acc[i][j] = z;
        }

    for (int k0 = 0; k0 < K; k0 += 64) {
#pragma unroll
        for (int i = 0; i < 4; i++) {
            int r = srow + i * 32;
            *(bf16x8*)&As[r * 72 + scol] = ld8(&A[(size_t)(tile_m + r) * K + k0 + scol]);
            *(bf16x8*)&Bs[r * 72 + scol] = ld8(&W[(size_t)(tile_n + r) * K + k0 + scol]);
        }
        __syncthreads();

#pragma unroll
        for (int kk = 0; kk < 2; kk++) {
            bf16x8 af[4], bfr[4];
#pragma unroll
            for (int i = 0; i < 4; i++)
                af[i] = *(const bf16x8*)&As[(wm + i * 16 + c) * 72 + kk * 32 + g * 8];
#pragma unroll
            for (int j = 0; j < 4; j++)
                bfr[j] = *(const bf16x8*)&Bs[(wn + j * 16 + c) * 72 + kk * 32 + g * 8];
#pragma unroll
            for (int i = 0; i < 4; i++)
#pragma unroll
                for (int j = 0; j < 4; j++)
                    acc[i][j] = MFMA_BF16(af[i], bfr[j], acc[i][j], 0, 0, 0);
        }
        __syncthreads();
    }

    float biasf[4];
    float lbv[4][8];
#pragma unroll
    for (int j = 0; j < 4; j++) {
        int col = tile_n + wn + j * 16 + c;           // global col
        biasf[j] = bias[col];
        f32x4 lb0 = *(const f32x4*)&LB[(size_t)col * 8];
        f32x4 lb1 = *(const f32x4*)&LB[(size_t)col * 8 + 4];
#pragma unroll
        for (int r = 0; r < 4; r++) { lbv[j][r] = lb0[r]; lbv[j][r + 4] = lb1[r]; }
    }
#pragma unroll
    for (int i = 0; i < 4; i++) {
#pragma unroll
        for (int rg = 0; rg < 4; rg++) {
            int row = tile_m + wm + i * 16 + g * 4 + rg;
            f32x4 xa0 = *(const f32x4*)&xA[(size_t)row * 8];
            f32x4 xa1 = *(const f32x4*)&xA[(size_t)row * 8 + 4];
#pragma unroll
            for (int j = 0; j < 4; j++) {
                float lora = xa0[0] * lbv[j][0] + xa0[1] * lbv[j][1] +
                             xa0[2] * lbv[j][2] + xa0[3] * lbv[j][3] +
                             xa1[0] * lbv[j][4] + xa1[1] * lbv[j][5] +
                             xa1[2] * lbv[j][6] + xa1[3] * lbv[j][7];
                float v = acc[i][j][rg] + biasf[j] + 2.0f * lora;
                int lcol = tn_loc + wn + j * 16 + c;
                if (Cf) Cf[(size_t)row * 1024 + lcol] = v;
                else    Cout[(size_t)row * 1024 + lcol] = (bf16_t)v;
            }
        }
    }
}

// ---------------------------------------------------------------------------
// Causal flash attention, all batches. Q/K/V: [4*2048,1024] bf16 (batch b =
// rows 2048b.., head h at cols h*64). Output IN PLACE into Q. Block =
// (qb, h, b), 4 waves x 16 q-rows, KV tile 64, scale = 0.125.
// Vt LDS layout d*72+(d>>4)*8+kv and P layout q*72+(q>>2)*8+kv rotate banks
// across the previously-4-way-conflicting lane quads (<=2-way, free).
// ---------------------------------------------------------------------------
#define VT_IDX(d, kv) ((d) * 72 + ((d) >> 4) * 8 + (kv))
#define PS_IDX(q, kv) ((q) * 72 + ((q) >> 2) * 8 + (kv))
#define PW_REGION 1168

__global__ __launch_bounds__(256) void attn_kernel(
    bf16_t* __restrict__ Q, const bf16_t* __restrict__ Kg,
    const bf16_t* __restrict__ Vg)
{
    __shared__ __align__(16) bf16_t Ks[64 * 72];            // K[kv][d]
    __shared__ __align__(16) bf16_t Vt[64 * 72 + 32];       // V^T[d][kv] swizzled
    __shared__ __align__(16) bf16_t Ps[4 * PW_REGION];      // per-wave P[q][kv]

    const int t    = threadIdx.x;
    const int lane = t & 63;
    const int w    = t >> 6;
    const int c    = lane & 15;
    const int g    = lane >> 4;
    const int qb = blockIdx.x, h = blockIdx.y, b = blockIdx.z;
    const int q0 = qb * 64;
    const size_t base = (size_t)b * 2048 * 1024;

    bf16x8 qf[2];
    {
        int qrow = q0 + w * 16 + c;
        const bf16_t* qp = Q + base + (size_t)qrow * 1024 + h * 64;
        qf[0] = *(const bf16x8*)&qp[g * 8];
        qf[1] = *(const bf16x8*)&qp[32 + g * 8];
    }

    f32x4 acc_o[4];
#pragma unroll
    for (int jd = 0; jd < 4; jd++) {
        f32x4 z = {0.f, 0.f, 0.f, 0.f};
        acc_o[jd] = z;
    }
    float m_run[4], l_run[4];
#pragma unroll
    for (int r = 0; r < 4; r++) { m_run[r] = NEG_BIG; l_run[r] = 0.f; }

    const int sr = t >> 2;           // staging kv row 0..63
    const int sc = (t & 3) * 16;     // staging d col {0,16,32,48}
    const int vtbase = VT_IDX(sc, sr);   // (sc+e)>>4 == sc>>4 for e<16

    for (int kt = 0; kt <= qb; kt++) {
        {
            const bf16_t* kp = Kg + base + (size_t)(kt * 64 + sr) * 1024 + h * 64 + sc;
            *(bf16x8*)&Ks[sr * 72 + sc]     = *(const bf16x8*)&kp[0];
            *(bf16x8*)&Ks[sr * 72 + sc + 8] = *(const bf16x8*)&kp[8];
            const bf16_t* vp = Vg + base + (size_t)(kt * 64 + sr) * 1024 + h * 64 + sc;
            bf16x8 v0 = *(const bf16x8*)&vp[0];
            bf16x8 v1 = *(const bf16x8*)&vp[8];
#pragma unroll
            for (int e = 0; e < 8; e++) Vt[vtbase + e * 72]       = v0[e];
#pragma unroll
            for (int e = 0; e < 8; e++) Vt[vtbase + (e + 8) * 72] = v1[e];
        }
        __syncthreads();

        f32x4 s[4];
#pragma unroll
        for (int j = 0; j < 4; j++) {
            f32x4 z = {0.f, 0.f, 0.f, 0.f};
            s[j] = z;
        }
#pragma unroll
        for (int kk = 0; kk < 2; kk++) {
            bf16x8 kf[4];
#pragma unroll
            for (int j = 0; j < 4; j++)
                kf[j] = *(const bf16x8*)&Ks[(j * 16 + c) * 72 + kk * 32 + g * 8];
#pragma unroll
            for (int j = 0; j < 4; j++)
                s[j] = MFMA_BF16(qf[kk], kf[j], s[j], 0, 0, 0);
        }

        float sv[4][4];
#pragma unroll
        for (int j = 0; j < 4; j++)
#pragma unroll
            for (int r = 0; r < 4; r++) sv[j][r] = s[j][r] * 0.125f;

        if (kt == qb) {   // diagonal block: causal mask
#pragma unroll
            for (int j = 0; j < 4; j++) {
                int kv = j * 16 + c;
#pragma unroll
                for (int r = 0; r < 4; r++) {
                    int q = w * 16 + g * 4 + r;
                    if (kv > q) sv[j][r] = NEG_BIG;
                }
            }
        }

        float alpha[4];
#pragma unroll
        for (int r = 0; r < 4; r++) {
            float mx = fmaxf(fmaxf(sv[0][r], sv[1][r]), fmaxf(sv[2][r], sv[3][r]));
            mx = fmaxf(mx, __shfl_xor(mx, 1));
            mx = fmaxf(mx, __shfl_xor(mx, 2));
            mx = fmaxf(mx, __shfl_xor(mx, 4));
            mx = fmaxf(mx, __shfl_xor(mx, 8));
            float mnew = fmaxf(m_run[r], mx);
            alpha[r] = __expf(m_run[r] - mnew);
            m_run[r] = mnew;
        }
        float pv[4][4];
#pragma unroll
        for (int j = 0; j < 4; j++)
#pragma unroll
            for (int r = 0; r < 4; r++) pv[j][r] = __expf(sv[j][r] - m_run[r]);
#pragma unroll
        for (int r = 0; r < 4; r++) {
            float sm = pv[0][r] + pv[1][r] + pv[2][r] + pv[3][r];
            sm += __shfl_xor(sm, 1);
            sm += __shfl_xor(sm, 2);
            sm += __shfl_xor(sm, 4);
            sm += __shfl_xor(sm, 8);
            l_run[r] = l_run[r] * alpha[r] + sm;
        }

        bf16_t* Pw = &Ps[w * PW_REGION];
#pragma unroll
        for (int j = 0; j < 4; j++)
#pragma unroll
            for (int r = 0; r < 4; r++)
                Pw[(g * 4 + r) * 72 + g * 8 + j * 16 + c] = (bf16_t)pv[j][r];

#pragma unroll
        for (int jd = 0; jd < 4; jd++)
#pragma unroll
            for (int r = 0; r < 4; r++) acc_o[jd][r] *= alpha[r];

        __syncthreads();

#pragma unroll
        for (int kkv = 0; kkv < 2; kkv++) {
            bf16x8 pf = *(const bf16x8*)&Pw[PS_IDX(c, kkv * 32 + g * 8)];
#pragma unroll
            for (int jd = 0; jd < 4; jd++) {
                bf16x8 vf = *(const bf16x8*)&Vt[VT_IDX(jd * 16 + c, kkv * 32 + g * 8)];
                acc_o[jd] = MFMA_BF16(pf, vf, acc_o[jd], 0, 0, 0);
            }
        }
        __syncthreads();
    }

#pragma unroll
    for (int jd = 0; jd < 4; jd++) {
#pragma unroll
        for (int r = 0; r < 4; r++) {
            int qrow = q0 + w * 16 + g * 4 + r;
            float v = acc_o[jd][r] / l_run[r];
            Q[base + (size_t)qrow * 1024 + h * 64 + jd * 16 + c] = (bf16_t)v;
        }
    }
}

// ---------------------------------------------------------------------------
extern "C" void kernel_launch(void* const* d_in, const int* in_sizes, int n_in,
                              void* d_out, int out_size, void* d_ws, size_t ws_size,
                              hipStream_t stream) {
    const float* x     = (const float*)d_in[0];   // [4,2048,1024] fp32
    const float* Wqkv  = (const float*)d_in[1];   // [3072,1024]
    const float* bqkv  = (const float*)d_in[2];   // [3072]
    const float* Aqkv  = (const float*)d_in[3];   // [8,1024]
    const float* Bqkv  = (const float*)d_in[4];   // [3072,8]
    const float* Wproj = (const float*)d_in[5];   // [1024,1024]
    const float* bproj = (const float*)d_in[6];   // [1024]
    const float* Aproj = (const float*)d_in[7];   // [8,1024]
    const float* Bproj = (const float*)d_in[8];   // [1024,8]
    float* out = (float*)d_out;                   // [4,2048,1024] fp32

    // workspace map (total 48.5 MiB — proven size):
    //   [0,     256K) : xa1 fp32 [8192*8]
    //   [256K,  512K) : xa2 fp32 [8192*8]
    //   [512K, 16.5M) : Qfull bf16 [8192*1024]  (attn output in place)
    //   [16.5M,32.5M) : Kfull bf16 [8192*1024]
    //   [32.5M,48.5M) : Vfull bf16 [8192*1024]
    char* ws = (char*)d_ws;
    float*  xa1   = (float*)ws;
    float*  xa2   = (float*)(ws + 262144);
    bf16_t* Qfull = (bf16_t*)(ws + 524288);
    bf16_t* Kfull = Qfull + (size_t)8192 * 1024;
    bf16_t* Vfull = Kfull + (size_t)8192 * 1024;

    // 1) xA for QKV LoRA (fp32 x direct)
    lora_xa_kernel<float><<<2048, 256, 0, stream>>>(x, Aqkv, xa1);

    // 2) QKV GEMM, all batches, inline fp32->bf16 staging
    gemm_bias_lora<float, float><<<dim3(24, 64), 256, 0, stream>>>(
        x, Wqkv, bqkv, xa1, Bqkv, Qfull, Kfull, Vfull, nullptr, 1024);

    // 3) causal MHA, all batches (output overwrites Qfull)
    attn_kernel<<<dim3(32, 16, 4), 256, 0, stream>>>(Qfull, Kfull, Vfull);

    // 4) xA for proj LoRA (reads attn output in Qfull)
    lora_xa_kernel<bf16_t><<<2048, 256, 0, stream>>>(Qfull, Aproj, xa2);

    // 5) proj GEMM: fp32 output -> d_out
    gemm_bias_lora<bf16_t, float><<<dim3(8, 64), 256, 0, stream>>>(
        Qfull, Wproj, bproj, xa2, Bproj,
        nullptr, nullptr, nullptr, out, 1024);
}

// Round 6
// 364.835 us; speedup vs baseline: 1.6841x; 1.4429x over previous
//
#include <hip/hip_runtime.h>
#include <hip/hip_bf16.h>

typedef __bf16 bf16_t;
typedef __bf16 bf16x8 __attribute__((ext_vector_type(8)));
typedef float  f32x4  __attribute__((ext_vector_type(4)));

#define MFMA_BF16 __builtin_amdgcn_mfma_f32_16x16x32_bf16
#define NEG_BIG  (-3.0e38f)

// load 8 contiguous elements as bf16x8, converting if source is fp32
__device__ inline bf16x8 ld8(const bf16_t* p) { return *(const bf16x8*)p; }
__device__ inline bf16x8 ld8(const float* p) {
    f32x4 a = *(const f32x4*)p;
    f32x4 b = *(const f32x4*)(p + 4);
    bf16x8 o;
    o[0] = (bf16_t)a[0]; o[1] = (bf16_t)a[1]; o[2] = (bf16_t)a[2]; o[3] = (bf16_t)a[3];
    o[4] = (bf16_t)b[0]; o[5] = (bf16_t)b[1]; o[6] = (bf16_t)b[2]; o[7] = (bf16_t)b[3];
    return o;
}

// ---------------------------------------------------------------------------
// LoRA first stage: out[m][r] = sum_k X[m][k] * A[r][k]
// X: [M,1024] (fp32 or bf16), A: [8,1024] fp32, out: [M,8] fp32. Wave/row.
// ---------------------------------------------------------------------------
template <typename TX>
__global__ __launch_bounds__(256) void lora_xa_kernel(
    const TX* __restrict__ X, const float* __restrict__ A,
    float* __restrict__ out)
{
    const int lane = threadIdx.x & 63;
    const int w    = threadIdx.x >> 6;
    const int m    = blockIdx.x * 4 + w;
    const TX* xp = X + (size_t)m * 1024;

    float acc[8];
#pragma unroll
    for (int r = 0; r < 8; r++) acc[r] = 0.f;

#pragma unroll 4
    for (int ci = 0; ci < 16; ci++) {
        int k = ci * 64 + lane;
        float xv = (float)xp[k];
#pragma unroll
        for (int r = 0; r < 8; r++) acc[r] += xv * A[r * 1024 + k];
    }
#pragma unroll
    for (int r = 0; r < 8; r++) {
        float v = acc[r];
        v += __shfl_xor(v, 1);  v += __shfl_xor(v, 2);  v += __shfl_xor(v, 4);
        v += __shfl_xor(v, 8);  v += __shfl_xor(v, 16); v += __shfl_xor(v, 32);
        if (lane == 0) out[m * 8 + r] = v;
    }
}

// ---------------------------------------------------------------------------
// GEMM: C[m][n] = sum_k A[m][k]*W[n][k] + bias[n] + 2*sum_r xA[m][r]*LB[n][r]
// A: [M,K] row-major (fp32 or bf16 — converted to bf16 during staging),
// W: [N,K] row-major (fp32 or bf16, B^T layout). bias/xA/LB fp32.
// Output: Cf!=nullptr -> fp32 [M,1024]; else bf16 routed C0/C1/C2 by segment.
// 128x128 tile, BK=64, 4 waves (2x2), 4x4 MFMA 16x16x32 per wave.
// ---------------------------------------------------------------------------
template <typename TA, typename TW>
__global__ __launch_bounds__(256) void gemm_bias_lora(
    const TA* __restrict__ A, const TW* __restrict__ W,
    const float* __restrict__ bias, const float* __restrict__ xA,
    const float* __restrict__ LB,
    bf16_t* __restrict__ C0, bf16_t* __restrict__ C1, bf16_t* __restrict__ C2,
    float* __restrict__ Cf, int K)
{
    __shared__ __align__(16) bf16_t As[128 * 72];
    __shared__ __align__(16) bf16_t Bs[128 * 72];

    const int t    = threadIdx.x;
    const int lane = t & 63;
    const int w    = t >> 6;
    const int wm   = (w >> 1) * 64;
    const int wn   = (w & 1) * 64;
    const int c    = lane & 15;
    const int g    = lane >> 4;
    const int tile_m = blockIdx.y * 128;
    const int tile_n = blockIdx.x * 128;

    const int seg    = tile_n >> 10;
    const int tn_loc = tile_n & 1023;
    bf16_t* __restrict__ Cout = (seg == 0) ? C0 : (seg == 1) ? C1 : C2;

    const int srow = t >> 3;             // 0..31
    const int scol = (t & 7) * 8;        // 0..56 step 8

    f32x4 acc[4][4];
#pragma unroll
    for (int i = 0; i < 4; i++)
#pragma unroll
        for (int j = 0; j < 4; j++) {
            f32x4 z = {0.f, 0.f, 0.f, 0.f};
            acc[i][j] = z;
        }

    for (int k0 = 0; k0 < K; k0 += 64) {
#pragma unroll
        for (int i = 0; i < 4; i++) {
            int r = srow + i * 32;
            *(bf16x8*)&As[r * 72 + scol] = ld8(&A[(size_t)(tile_m + r) * K + k0 + scol]);
            *(bf16x8*)&Bs[r * 72 + scol] = ld8(&W[(size_t)(tile_n + r) * K + k0 + scol]);
        }
        __syncthreads();

#pragma unroll
        for (int kk = 0; kk < 2; kk++) {
            bf16x8 af[4], bfr[4];
#pragma unroll
            for (int i = 0; i < 4; i++)
                af[i] = *(const bf16x8*)&As[(wm + i * 16 + c) * 72 + kk * 32 + g * 8];
#pragma unroll
            for (int j = 0; j < 4; j++)
                bfr[j] = *(const bf16x8*)&Bs[(wn + j * 16 + c) * 72 + kk * 32 + g * 8];
#pragma unroll
            for (int i = 0; i < 4; i++)
#pragma unroll
                for (int j = 0; j < 4; j++)
                    acc[i][j] = MFMA_BF16(af[i], bfr[j], acc[i][j], 0, 0, 0);
        }
        __syncthreads();
    }

    float biasf[4];
    float lbv[4][8];
#pragma unroll
    for (int j = 0; j < 4; j++) {
        int col = tile_n + wn + j * 16 + c;           // global col
        biasf[j] = bias[col];
        f32x4 lb0 = *(const f32x4*)&LB[(size_t)col * 8];
        f32x4 lb1 = *(const f32x4*)&LB[(size_t)col * 8 + 4];
#pragma unroll
        for (int r = 0; r < 4; r++) { lbv[j][r] = lb0[r]; lbv[j][r + 4] = lb1[r]; }
    }
#pragma unroll
    for (int i = 0; i < 4; i++) {
#pragma unroll
        for (int rg = 0; rg < 4; rg++) {
            int row = tile_m + wm + i * 16 + g * 4 + rg;
            f32x4 xa0 = *(const f32x4*)&xA[(size_t)row * 8];
            f32x4 xa1 = *(const f32x4*)&xA[(size_t)row * 8 + 4];
#pragma unroll
            for (int j = 0; j < 4; j++) {
                float lora = xa0[0] * lbv[j][0] + xa0[1] * lbv[j][1] +
                             xa0[2] * lbv[j][2] + xa0[3] * lbv[j][3] +
                             xa1[0] * lbv[j][4] + xa1[1] * lbv[j][5] +
                             xa1[2] * lbv[j][6] + xa1[3] * lbv[j][7];
                float v = acc[i][j][rg] + biasf[j] + 2.0f * lora;
                int lcol = tn_loc + wn + j * 16 + c;
                if (Cf) Cf[(size_t)row * 1024 + lcol] = v;
                else    Cout[(size_t)row * 1024 + lcol] = (bf16_t)v;
            }
        }
    }
}

// ---------------------------------------------------------------------------
// Causal flash attention, all batches. Q/K/V: [4*2048,1024] bf16.
// 1D grid of 2048 blocks, decoded LONGEST-qb FIRST (kills scheduler tail).
// Per KV-iter: 2 barriers (P buffer is per-wave -> no mid barrier); next K/V
// tile prefetched into registers during compute (hides global latency);
// row-sum l accumulated via MFMA with B=ones (no sum-shuffles).
// Vt layout d*72+(d>>4)*8+kv, P layout q*72+(q>>2)*8+kv: <=2-way LDS banks.
// ---------------------------------------------------------------------------
#define VT_IDX(d, kv) ((d) * 72 + ((d) >> 4) * 8 + (kv))
#define PS_IDX(q, kv) ((q) * 72 + ((q) >> 2) * 8 + (kv))
#define PW_REGION 1168

__global__ __launch_bounds__(256) void attn_kernel(
    bf16_t* __restrict__ Q, const bf16_t* __restrict__ Kg,
    const bf16_t* __restrict__ Vg)
{
    __shared__ __align__(16) bf16_t Ks[64 * 72];            // K[kv][d]
    __shared__ __align__(16) bf16_t Vt[64 * 72 + 32];       // V^T[d][kv] swizzled
    __shared__ __align__(16) bf16_t Ps[4 * PW_REGION];      // per-wave P[q][kv]

    const int t    = threadIdx.x;
    const int lane = t & 63;
    const int w    = t >> 6;
    const int c    = lane & 15;
    const int g    = lane >> 4;

    // longest-first decode: ids 0..63 -> qb=31, next 64 -> qb=30, ...
    const int id = blockIdx.x;
    const int qb = 31 - (id >> 6);
    const int h  = id & 15;
    const int b  = (id >> 4) & 3;
    const int q0 = qb * 64;
    const size_t base = (size_t)b * 2048 * 1024;

    bf16x8 qf[2];
    {
        int qrow = q0 + w * 16 + c;
        const bf16_t* qp = Q + base + (size_t)qrow * 1024 + h * 64;
        qf[0] = *(const bf16x8*)&qp[g * 8];
        qf[1] = *(const bf16x8*)&qp[32 + g * 8];
    }

    bf16x8 ones;
#pragma unroll
    for (int e = 0; e < 8; e++) ones[e] = (bf16_t)1.0f;

    f32x4 acc_o[4];
#pragma unroll
    for (int jd = 0; jd < 4; jd++) {
        f32x4 z = {0.f, 0.f, 0.f, 0.f};
        acc_o[jd] = z;
    }
    f32x4 acc_l = {0.f, 0.f, 0.f, 0.f};    // row-sum accumulator (ones-trick)
    float m_run[4];
#pragma unroll
    for (int r = 0; r < 4; r++) m_run[r] = NEG_BIG;

    const int sr = t >> 2;           // staging kv row 0..63
    const int sc = (t & 3) * 16;     // staging d col {0,16,32,48}
    const int vtbase = VT_IDX(sc, sr);

    // preload tile kt=0 into registers
    bf16x8 kr0, kr1, vr0, vr1;
    {
        const bf16_t* kp = Kg + base + (size_t)sr * 1024 + h * 64 + sc;
        kr0 = *(const bf16x8*)&kp[0];
        kr1 = *(const bf16x8*)&kp[8];
        const bf16_t* vp = Vg + base + (size_t)sr * 1024 + h * 64 + sc;
        vr0 = *(const bf16x8*)&vp[0];
        vr1 = *(const bf16x8*)&vp[8];
    }

    for (int kt = 0; kt <= qb; kt++) {
        if (kt > 0) __syncthreads();          // prev iter's LDS reads done
        // ---- stage K/V from prefetch regs ----
        *(bf16x8*)&Ks[sr * 72 + sc]     = kr0;
        *(bf16x8*)&Ks[sr * 72 + sc + 8] = kr1;
#pragma unroll
        for (int e = 0; e < 8; e++) Vt[vtbase + e * 72]       = vr0[e];
#pragma unroll
        for (int e = 0; e < 8; e++) Vt[vtbase + (e + 8) * 72] = vr1[e];
        __syncthreads();

        // ---- prefetch next tile (latency hidden behind compute below) ----
        if (kt < qb) {
            const bf16_t* kp = Kg + base + (size_t)((kt + 1) * 64 + sr) * 1024 + h * 64 + sc;
            kr0 = *(const bf16x8*)&kp[0];
            kr1 = *(const bf16x8*)&kp[8];
            const bf16_t* vp = Vg + base + (size_t)((kt + 1) * 64 + sr) * 1024 + h * 64 + sc;
            vr0 = *(const bf16x8*)&vp[0];
            vr1 = *(const bf16x8*)&vp[8];
        }

        // ---- S = Q K^T ----
        f32x4 s[4];
#pragma unroll
        for (int j = 0; j < 4; j++) {
            f32x4 z = {0.f, 0.f, 0.f, 0.f};
            s[j] = z;
        }
#pragma unroll
        for (int kk = 0; kk < 2; kk++) {
            bf16x8 kf[4];
#pragma unroll
            for (int j = 0; j < 4; j++)
                kf[j] = *(const bf16x8*)&Ks[(j * 16 + c) * 72 + kk * 32 + g * 8];
#pragma unroll
            for (int j = 0; j < 4; j++)
                s[j] = MFMA_BF16(qf[kk], kf[j], s[j], 0, 0, 0);
        }

        float sv[4][4];
#pragma unroll
        for (int j = 0; j < 4; j++)
#pragma unroll
            for (int r = 0; r < 4; r++) sv[j][r] = s[j][r] * 0.125f;

        if (kt == qb) {   // diagonal block: causal mask
#pragma unroll
            for (int j = 0; j < 4; j++) {
                int kv = j * 16 + c;
#pragma unroll
                for (int r = 0; r < 4; r++) {
                    int q = w * 16 + g * 4 + r;
                    if (kv > q) sv[j][r] = NEG_BIG;
                }
            }
        }

        // ---- online max (shfl) + rescale ----
        float alpha[4];
#pragma unroll
        for (int r = 0; r < 4; r++) {
            float mx = fmaxf(fmaxf(sv[0][r], sv[1][r]), fmaxf(sv[2][r], sv[3][r]));
            mx = fmaxf(mx, __shfl_xor(mx, 1));
            mx = fmaxf(mx, __shfl_xor(mx, 2));
            mx = fmaxf(mx, __shfl_xor(mx, 4));
            mx = fmaxf(mx, __shfl_xor(mx, 8));
            float mnew = fmaxf(m_run[r], mx);
            alpha[r] = __expf(m_run[r] - mnew);
            m_run[r] = mnew;
        }
        float pv[4][4];
#pragma unroll
        for (int j = 0; j < 4; j++)
#pragma unroll
            for (int r = 0; r < 4; r++) pv[j][r] = __expf(sv[j][r] - m_run[r]);

        // ---- write P (per-wave region; same-wave read below, no barrier) ----
        bf16_t* Pw = &Ps[w * PW_REGION];
#pragma unroll
        for (int j = 0; j < 4; j++)
#pragma unroll
            for (int r = 0; r < 4; r++)
                Pw[(g * 4 + r) * 72 + g * 8 + j * 16 + c] = (bf16_t)pv[j][r];

#pragma unroll
        for (int jd = 0; jd < 4; jd++)
#pragma unroll
            for (int r = 0; r < 4; r++) acc_o[jd][r] *= alpha[r];
#pragma unroll
        for (int r = 0; r < 4; r++) acc_l[r] *= alpha[r];

        // ---- O += P @ V ; l += P @ 1 ----
#pragma unroll
        for (int kkv = 0; kkv < 2; kkv++) {
            bf16x8 pf = *(const bf16x8*)&Pw[PS_IDX(c, kkv * 32 + g * 8)];
#pragma unroll
            for (int jd = 0; jd < 4; jd++) {
                bf16x8 vf = *(const bf16x8*)&Vt[VT_IDX(jd * 16 + c, kkv * 32 + g * 8)];
                acc_o[jd] = MFMA_BF16(pf, vf, acc_o[jd], 0, 0, 0);
            }
            acc_l = MFMA_BF16(pf, ones, acc_l, 0, 0, 0);
        }
    }

#pragma unroll
    for (int jd = 0; jd < 4; jd++) {
#pragma unroll
        for (int r = 0; r < 4; r++) {
            int qrow = q0 + w * 16 + g * 4 + r;
            float v = acc_o[jd][r] / acc_l[r];
            Q[base + (size_t)qrow * 1024 + h * 64 + jd * 16 + c] = (bf16_t)v;
        }
    }
}

// ---------------------------------------------------------------------------
extern "C" void kernel_launch(void* const* d_in, const int* in_sizes, int n_in,
                              void* d_out, int out_size, void* d_ws, size_t ws_size,
                              hipStream_t stream) {
    const float* x     = (const float*)d_in[0];   // [4,2048,1024] fp32
    const float* Wqkv  = (const float*)d_in[1];   // [3072,1024]
    const float* bqkv  = (const float*)d_in[2];   // [3072]
    const float* Aqkv  = (const float*)d_in[3];   // [8,1024]
    const float* Bqkv  = (const float*)d_in[4];   // [3072,8]
    const float* Wproj = (const float*)d_in[5];   // [1024,1024]
    const float* bproj = (const float*)d_in[6];   // [1024]
    const float* Aproj = (const float*)d_in[7];   // [8,1024]
    const float* Bproj = (const float*)d_in[8];   // [1024,8]
    float* out = (float*)d_out;                   // [4,2048,1024] fp32

    // workspace map (total 48.5 MiB — proven size):
    //   [0,     256K) : xa1 fp32 [8192*8]
    //   [256K,  512K) : xa2 fp32 [8192*8]
    //   [512K, 16.5M) : Qfull bf16 [8192*1024]  (attn output in place)
    //   [16.5M,32.5M) : Kfull bf16 [8192*1024]
    //   [32.5M,48.5M) : Vfull bf16 [8192*1024]
    char* ws = (char*)d_ws;
    float*  xa1   = (float*)ws;
    float*  xa2   = (float*)(ws + 262144);
    bf16_t* Qfull = (bf16_t*)(ws + 524288);
    bf16_t* Kfull = Qfull + (size_t)8192 * 1024;
    bf16_t* Vfull = Kfull + (size_t)8192 * 1024;

    // 1) xA for QKV LoRA (fp32 x direct)
    lora_xa_kernel<float><<<2048, 256, 0, stream>>>(x, Aqkv, xa1);

    // 2) QKV GEMM, all batches, inline fp32->bf16 staging
    gemm_bias_lora<float, float><<<dim3(24, 64), 256, 0, stream>>>(
        x, Wqkv, bqkv, xa1, Bqkv, Qfull, Kfull, Vfull, nullptr, 1024);

    // 3) causal MHA, all batches (output overwrites Qfull)
    attn_kernel<<<2048, 256, 0, stream>>>(Qfull, Kfull, Vfull);

    // 4) xA for proj LoRA (reads attn output in Qfull)
    lora_xa_kernel<bf16_t><<<2048, 256, 0, stream>>>(Qfull, Aproj, xa2);

    // 5) proj GEMM: fp32 output -> d_out
    gemm_bias_lora<bf16_t, float><<<dim3(8, 64), 256, 0, stream>>>(
        Qfull, Wproj, bproj, xa2, Bproj,
        nullptr, nullptr, nullptr, out, 1024);
}

// Round 7
// 342.101 us; speedup vs baseline: 1.7960x; 1.0665x over previous
//
#include <hip/hip_runtime.h>
#include <hip/hip_bf16.h>

typedef __bf16 bf16_t;
typedef __bf16 bf16x8 __attribute__((ext_vector_type(8)));
typedef float  f32x4  __attribute__((ext_vector_type(4)));

#define MFMA_BF16 __builtin_amdgcn_mfma_f32_16x16x32_bf16
#define NEG_BIG  (-3.0e38f)

// async global->LDS 16B copy (gfx950 dwordx4 variant)
__device__ __forceinline__ void load16_lds(const bf16_t* g, bf16_t* l) {
    __builtin_amdgcn_global_load_lds(
        (const __attribute__((address_space(1))) void*)g,
        (__attribute__((address_space(3))) void*)l, 16, 0, 0);
}

// load 8 contiguous elements as bf16x8, converting if source is fp32
__device__ inline bf16x8 ld8(const bf16_t* p) { return *(const bf16x8*)p; }
__device__ inline bf16x8 ld8(const float* p) {
    f32x4 a = *(const f32x4*)p;
    f32x4 b = *(const f32x4*)(p + 4);
    bf16x8 o;
    o[0] = (bf16_t)a[0]; o[1] = (bf16_t)a[1]; o[2] = (bf16_t)a[2]; o[3] = (bf16_t)a[3];
    o[4] = (bf16_t)b[0]; o[5] = (bf16_t)b[1]; o[6] = (bf16_t)b[2]; o[7] = (bf16_t)b[3];
    return o;
}

// ---------------------------------------------------------------------------
// fp32 -> bf16, 8 elems/thread (n = grid*2048)
// ---------------------------------------------------------------------------
__global__ __launch_bounds__(256) void cvt_f32_bf16(
    const float* __restrict__ in, bf16_t* __restrict__ out)
{
    size_t i = ((size_t)blockIdx.x * 256 + threadIdx.x) * 8;
    *(bf16x8*)&out[i] = ld8(&in[i]);
}

// ---------------------------------------------------------------------------
// LoRA first stage: out[m][r] = sum_k X[m][k] * A[r][k]
// ---------------------------------------------------------------------------
template <typename TX>
__global__ __launch_bounds__(256) void lora_xa_kernel(
    const TX* __restrict__ X, const float* __restrict__ A,
    float* __restrict__ out)
{
    const int lane = threadIdx.x & 63;
    const int w    = threadIdx.x >> 6;
    const int m    = blockIdx.x * 4 + w;
    const TX* xp = X + (size_t)m * 1024;

    float acc[8];
#pragma unroll
    for (int r = 0; r < 8; r++) acc[r] = 0.f;

#pragma unroll 4
    for (int ci = 0; ci < 16; ci++) {
        int k = ci * 64 + lane;
        float xv = (float)xp[k];
#pragma unroll
        for (int r = 0; r < 8; r++) acc[r] += xv * A[r * 1024 + k];
    }
#pragma unroll
    for (int r = 0; r < 8; r++) {
        float v = acc[r];
        v += __shfl_xor(v, 1);  v += __shfl_xor(v, 2);  v += __shfl_xor(v, 4);
        v += __shfl_xor(v, 8);  v += __shfl_xor(v, 16); v += __shfl_xor(v, 32);
        if (lane == 0) out[m * 8 + r] = v;
    }
}

// ---------------------------------------------------------------------------
// Shared epilogue: bias + rank-8 LoRA + routed store.
// ---------------------------------------------------------------------------
__device__ __forceinline__ void gemm_epilogue(
    f32x4 (&acc)[4][4], const float* bias, const float* xA, const float* LB,
    bf16_t* C0, bf16_t* C1, bf16_t* C2, float* Cf,
    int tile_m, int tile_n, int wm, int wn, int c, int g)
{
    const int seg    = tile_n >> 10;
    const int tn_loc = tile_n & 1023;
    bf16_t* Cout = (seg == 0) ? C0 : (seg == 1) ? C1 : C2;

    float biasf[4];
    float lbv[4][8];
#pragma unroll
    for (int j = 0; j < 4; j++) {
        int col = tile_n + wn + j * 16 + c;
        biasf[j] = bias[col];
        f32x4 lb0 = *(const f32x4*)&LB[(size_t)col * 8];
        f32x4 lb1 = *(const f32x4*)&LB[(size_t)col * 8 + 4];
#pragma unroll
        for (int r = 0; r < 4; r++) { lbv[j][r] = lb0[r]; lbv[j][r + 4] = lb1[r]; }
    }
#pragma unroll
    for (int i = 0; i < 4; i++) {
#pragma unroll
        for (int rg = 0; rg < 4; rg++) {
            int row = tile_m + wm + i * 16 + g * 4 + rg;
            f32x4 xa0 = *(const f32x4*)&xA[(size_t)row * 8];
            f32x4 xa1 = *(const f32x4*)&xA[(size_t)row * 8 + 4];
#pragma unroll
            for (int j = 0; j < 4; j++) {
                float lora = xa0[0] * lbv[j][0] + xa0[1] * lbv[j][1] +
                             xa0[2] * lbv[j][2] + xa0[3] * lbv[j][3] +
                             xa1[0] * lbv[j][4] + xa1[1] * lbv[j][5] +
                             xa1[2] * lbv[j][6] + xa1[3] * lbv[j][7];
                float v = acc[i][j][rg] + biasf[j] + 2.0f * lora;
                int lcol = tn_loc + wn + j * 16 + c;
                if (Cf) Cf[(size_t)row * 1024 + lcol] = v;
                else    Cout[(size_t)row * 1024 + lcol] = (bf16_t)v;
            }
        }
    }
}

// ---------------------------------------------------------------------------
// FALLBACK GEMM (small-ws path): VGPR staging, inline fp32->bf16 cvt.
// ---------------------------------------------------------------------------
template <typename TA, typename TW>
__global__ __launch_bounds__(256) void gemm_bias_lora(
    const TA* __restrict__ A, const TW* __restrict__ W,
    const float* __restrict__ bias, const float* __restrict__ xA,
    const float* __restrict__ LB,
    bf16_t* __restrict__ C0, bf16_t* __restrict__ C1, bf16_t* __restrict__ C2,
    float* __restrict__ Cf, int K)
{
    __shared__ __align__(16) bf16_t As[128 * 72];
    __shared__ __align__(16) bf16_t Bs[128 * 72];

    const int t    = threadIdx.x;
    const int lane = t & 63;
    const int w    = t >> 6;
    const int wm   = (w >> 1) * 64;
    const int wn   = (w & 1) * 64;
    const int c    = lane & 15;
    const int g    = lane >> 4;
    const int tile_m = blockIdx.y * 128;
    const int tile_n = blockIdx.x * 128;

    const int srow = t >> 3;
    const int scol = (t & 7) * 8;

    f32x4 acc[4][4];
#pragma unroll
    for (int i = 0; i < 4; i++)
#pragma unroll
        for (int j = 0; j < 4; j++) {
            f32x4 z = {0.f, 0.f, 0.f, 0.f};
            acc[i][j] = z;
        }

    for (int k0 = 0; k0 < K; k0 += 64) {
#pragma unroll
        for (int i = 0; i < 4; i++) {
            int r = srow + i * 32;
            *(bf16x8*)&As[r * 72 + scol] = ld8(&A[(size_t)(tile_m + r) * K + k0 + scol]);
            *(bf16x8*)&Bs[r * 72 + scol] = ld8(&W[(size_t)(tile_n + r) * K + k0 + scol]);
        }
        __syncthreads();

#pragma unroll
        for (int kk = 0; kk < 2; kk++) {
            bf16x8 af[4], bfr[4];
#pragma unroll
            for (int i = 0; i < 4; i++)
                af[i] = *(const bf16x8*)&As[(wm + i * 16 + c) * 72 + kk * 32 + g * 8];
#pragma unroll
            for (int j = 0; j < 4; j++)
                bfr[j] = *(const bf16x8*)&Bs[(wn + j * 16 + c) * 72 + kk * 32 + g * 8];
#pragma unroll
            for (int i = 0; i < 4; i++)
#pragma unroll
                for (int j = 0; j < 4; j++)
                    acc[i][j] = MFMA_BF16(af[i], bfr[j], acc[i][j], 0, 0, 0);
        }
        __syncthreads();
    }
    gemm_epilogue(acc, bias, xA, LB, C0, C1, C2, Cf, tile_m, tile_n, wm, wn, c, g);
}

// ---------------------------------------------------------------------------
// ASYNC GEMM (m97 structure): bf16 A/W, global_load_lds width=16 staging,
// unpadded LDS [128][64] with XOR swizzle (k8 ^ (row&7)) so fragment
// ds_read_b128s are <=2-way bank-conflicted (free). Staging LDS dest is
// lane-linear (slot = issue*256 + t), per-lane GLOBAL address carries the
// swizzle. 128x128 tile, BK=64, 4 waves, 4x4 MFMA 16x16x32.
// ---------------------------------------------------------------------------
#define AS_OFF(row, q) ((row) * 64 + (((q) ^ ((row) & 7)) * 8))

__global__ __launch_bounds__(256) void gemm_async(
    const bf16_t* __restrict__ A, const bf16_t* __restrict__ W,
    const float* __restrict__ bias, const float* __restrict__ xA,
    const float* __restrict__ LB,
    bf16_t* __restrict__ C0, bf16_t* __restrict__ C1, bf16_t* __restrict__ C2,
    float* __restrict__ Cf, int K)
{
    __shared__ __align__(16) bf16_t As[128 * 64];
    __shared__ __align__(16) bf16_t Bs[128 * 64];

    const int t    = threadIdx.x;
    const int lane = t & 63;
    const int w    = t >> 6;
    const int wm   = (w >> 1) * 64;
    const int wn   = (w & 1) * 64;
    const int c    = lane & 15;
    const int g    = lane >> 4;
    const int tile_m = blockIdx.y * 128;
    const int tile_n = blockIdx.x * 128;

    const int trow = t >> 3;                   // 0..31
    const int k8   = (t & 7) ^ (trow & 7);     // swizzled k-chunk for staging
    const bf16_t* Ab = A + (size_t)tile_m * K + k8 * 8;
    const bf16_t* Wb = W + (size_t)tile_n * K + k8 * 8;

    f32x4 acc[4][4];
#pragma unroll
    for (int i = 0; i < 4; i++)
#pragma unroll
        for (int j = 0; j < 4; j++) {
            f32x4 z = {0.f, 0.f, 0.f, 0.f};
            acc[i][j] = z;
        }

    for (int k0 = 0; k0 < K; k0 += 64) {
        // stage: 4 issues x 2 tiles, 16B/lane, lane-linear LDS slots
#pragma unroll
        for (int i = 0; i < 4; i++) {
            int row = i * 32 + trow;
            load16_lds(&Ab[(size_t)row * K + k0], &As[(i * 256 + t) * 8]);
            load16_lds(&Wb[(size_t)row * K + k0], &Bs[(i * 256 + t) * 8]);
        }
        __syncthreads();   // drains vmcnt(0) then barrier

#pragma unroll
        for (int kk = 0; kk < 2; kk++) {
            bf16x8 af[4], bfr[4];
#pragma unroll
            for (int i = 0; i < 4; i++)
                af[i] = *(const bf16x8*)&As[AS_OFF(wm + i * 16 + c, kk * 4 + g)];
#pragma unroll
            for (int j = 0; j < 4; j++)
                bfr[j] = *(const bf16x8*)&Bs[AS_OFF(wn + j * 16 + c, kk * 4 + g)];
#pragma unroll
            for (int i = 0; i < 4; i++)
#pragma unroll
                for (int j = 0; j < 4; j++)
                    acc[i][j] = MFMA_BF16(af[i], bfr[j], acc[i][j], 0, 0, 0);
        }
        __syncthreads();
    }
    gemm_epilogue(acc, bias, xA, LB, C0, C1, C2, Cf, tile_m, tile_n, wm, wn, c, g);
}

// ---------------------------------------------------------------------------
// Causal flash attention, all batches. 1D grid, longest-qb-first decode.
// 2 barriers/iter; next K/V tile prefetched into regs; row-sum l via MFMA
// ones-trick. Vt/P layouts bank-rotated (<=2-way).
// ---------------------------------------------------------------------------
#define VT_IDX(d, kv) ((d) * 72 + ((d) >> 4) * 8 + (kv))
#define PS_IDX(q, kv) ((q) * 72 + ((q) >> 2) * 8 + (kv))
#define PW_REGION 1168

__global__ __launch_bounds__(256) void attn_kernel(
    bf16_t* __restrict__ Q, const bf16_t* __restrict__ Kg,
    const bf16_t* __restrict__ Vg)
{
    __shared__ __align__(16) bf16_t Ks[64 * 72];
    __shared__ __align__(16) bf16_t Vt[64 * 72 + 32];
    __shared__ __align__(16) bf16_t Ps[4 * PW_REGION];

    const int t    = threadIdx.x;
    const int lane = t & 63;
    const int w    = t >> 6;
    const int c    = lane & 15;
    const int g    = lane >> 4;

    const int id = blockIdx.x;
    const int qb = 31 - (id >> 6);
    const int h  = id & 15;
    const int b  = (id >> 4) & 3;
    const int q0 = qb * 64;
    const size_t base = (size_t)b * 2048 * 1024;

    bf16x8 qf[2];
    {
        int qrow = q0 + w * 16 + c;
        const bf16_t* qp = Q + base + (size_t)qrow * 1024 + h * 64;
        qf[0] = *(const bf16x8*)&qp[g * 8];
        qf[1] = *(const bf16x8*)&qp[32 + g * 8];
    }

    bf16x8 ones;
#pragma unroll
    for (int e = 0; e < 8; e++) ones[e] = (bf16_t)1.0f;

    f32x4 acc_o[4];
#pragma unroll
    for (int jd = 0; jd < 4; jd++) {
        f32x4 z = {0.f, 0.f, 0.f, 0.f};
        acc_o[jd] = z;
    }
    f32x4 acc_l = {0.f, 0.f, 0.f, 0.f};
    float m_run[4];
#pragma unroll
    for (int r = 0; r < 4; r++) m_run[r] = NEG_BIG;

    const int sr = t >> 2;
    const int sc = (t & 3) * 16;
    const int vtbase = VT_IDX(sc, sr);

    bf16x8 kr0, kr1, vr0, vr1;
    {
        const bf16_t* kp = Kg + base + (size_t)sr * 1024 + h * 64 + sc;
        kr0 = *(const bf16x8*)&kp[0];
        kr1 = *(const bf16x8*)&kp[8];
        const bf16_t* vp = Vg + base + (size_t)sr * 1024 + h * 64 + sc;
        vr0 = *(const bf16x8*)&vp[0];
        vr1 = *(const bf16x8*)&vp[8];
    }

    for (int kt = 0; kt <= qb; kt++) {
        if (kt > 0) __syncthreads();
        *(bf16x8*)&Ks[sr * 72 + sc]     = kr0;
        *(bf16x8*)&Ks[sr * 72 + sc + 8] = kr1;
#pragma unroll
        for (int e = 0; e < 8; e++) Vt[vtbase + e * 72]       = vr0[e];
#pragma unroll
        for (int e = 0; e < 8; e++) Vt[vtbase + (e + 8) * 72] = vr1[e];
        __syncthreads();

        if (kt < qb) {
            const bf16_t* kp = Kg + base + (size_t)((kt + 1) * 64 + sr) * 1024 + h * 64 + sc;
            kr0 = *(const bf16x8*)&kp[0];
            kr1 = *(const bf16x8*)&kp[8];
            const bf16_t* vp = Vg + base + (size_t)((kt + 1) * 64 + sr) * 1024 + h * 64 + sc;
            vr0 = *(const bf16x8*)&vp[0];
            vr1 = *(const bf16x8*)&vp[8];
        }

        f32x4 s[4];
#pragma unroll
        for (int j = 0; j < 4; j++) {
            f32x4 z = {0.f, 0.f, 0.f, 0.f};
            s[j] = z;
        }
#pragma unroll
        for (int kk = 0; kk < 2; kk++) {
            bf16x8 kf[4];
#pragma unroll
            for (int j = 0; j < 4; j++)
                kf[j] = *(const bf16x8*)&Ks[(j * 16 + c) * 72 + kk * 32 + g * 8];
#pragma unroll
            for (int j = 0; j < 4; j++)
                s[j] = MFMA_BF16(qf[kk], kf[j], s[j], 0, 0, 0);
        }

        float sv[4][4];
#pragma unroll
        for (int j = 0; j < 4; j++)
#pragma unroll
            for (int r = 0; r < 4; r++) sv[j][r] = s[j][r] * 0.125f;

        if (kt == qb) {
#pragma unroll
            for (int j = 0; j < 4; j++) {
                int kv = j * 16 + c;
#pragma unroll
                for (int r = 0; r < 4; r++) {
                    int q = w * 16 + g * 4 + r;
                    if (kv > q) sv[j][r] = NEG_BIG;
                }
            }
        }

        float alpha[4];
#pragma unroll
        for (int r = 0; r < 4; r++) {
            float mx = fmaxf(fmaxf(sv[0][r], sv[1][r]), fmaxf(sv[2][r], sv[3][r]));
            mx = fmaxf(mx, __shfl_xor(mx, 1));
            mx = fmaxf(mx, __shfl_xor(mx, 2));
            mx = fmaxf(mx, __shfl_xor(mx, 4));
            mx = fmaxf(mx, __shfl_xor(mx, 8));
            float mnew = fmaxf(m_run[r], mx);
            alpha[r] = __expf(m_run[r] - mnew);
            m_run[r] = mnew;
        }
        float pv[4][4];
#pragma unroll
        for (int j = 0; j < 4; j++)
#pragma unroll
            for (int r = 0; r < 4; r++) pv[j][r] = __expf(sv[j][r] - m_run[r]);

        bf16_t* Pw = &Ps[w * PW_REGION];
#pragma unroll
        for (int j = 0; j < 4; j++)
#pragma unroll
            for (int r = 0; r < 4; r++)
                Pw[(g * 4 + r) * 72 + g * 8 + j * 16 + c] = (bf16_t)pv[j][r];

#pragma unroll
        for (int jd = 0; jd < 4; jd++)
#pragma unroll
            for (int r = 0; r < 4; r++) acc_o[jd][r] *= alpha[r];
#pragma unroll
        for (int r = 0; r < 4; r++) acc_l[r] *= alpha[r];

#pragma unroll
        for (int kkv = 0; kkv < 2; kkv++) {
            bf16x8 pf = *(const bf16x8*)&Pw[PS_IDX(c, kkv * 32 + g * 8)];
#pragma unroll
            for (int jd = 0; jd < 4; jd++) {
                bf16x8 vf = *(const bf16x8*)&Vt[VT_IDX(jd * 16 + c, kkv * 32 + g * 8)];
                acc_o[jd] = MFMA_BF16(pf, vf, acc_o[jd], 0, 0, 0);
            }
            acc_l = MFMA_BF16(pf, ones, acc_l, 0, 0, 0);
        }
    }

#pragma unroll
    for (int jd = 0; jd < 4; jd++) {
#pragma unroll
        for (int r = 0; r < 4; r++) {
            int qrow = q0 + w * 16 + g * 4 + r;
            float v = acc_o[jd][r] / acc_l[r];
            Q[base + (size_t)qrow * 1024 + h * 64 + jd * 16 + c] = (bf16_t)v;
        }
    }
}

// ---------------------------------------------------------------------------
extern "C" void kernel_launch(void* const* d_in, const int* in_sizes, int n_in,
                              void* d_out, int out_size, void* d_ws, size_t ws_size,
                              hipStream_t stream) {
    const float* x     = (const float*)d_in[0];
    const float* Wqkv  = (const float*)d_in[1];
    const float* bqkv  = (const float*)d_in[2];
    const float* Aqkv  = (const float*)d_in[3];
    const float* Bqkv  = (const float*)d_in[4];
    const float* Wproj = (const float*)d_in[5];
    const float* bproj = (const float*)d_in[6];
    const float* Aproj = (const float*)d_in[7];
    const float* Bproj = (const float*)d_in[8];
    float* out = (float*)d_out;

    char* ws = (char*)d_ws;
    const size_t MB = 1024 * 1024;
    const bool big = ws_size >= (size_t)(72.5 * 1024 * 1024) + 65536;

    if (big) {
        // big path: pre-converted bf16 operands + async (m97-style) GEMMs
        //   [0,256K) xa1 | [256K,512K) xa2 | x16 16M | Wqkv16 6M | Wproj16 2M
        //   | Qfull 16M | Kfull 16M | Vfull 16M   (72.5 MiB)
        float*  xa1    = (float*)ws;
        float*  xa2    = (float*)(ws + 262144);
        bf16_t* x16    = (bf16_t*)(ws + 524288);
        bf16_t* Wqkv16 = x16 + (size_t)8192 * 1024;
        bf16_t* Wproj16= Wqkv16 + (size_t)3072 * 1024;
        bf16_t* Qfull  = Wproj16 + (size_t)1024 * 1024;
        bf16_t* Kfull  = Qfull + (size_t)8192 * 1024;
        bf16_t* Vfull  = Kfull + (size_t)8192 * 1024;

        cvt_f32_bf16<<<4096, 256, 0, stream>>>(x, x16);
        cvt_f32_bf16<<<1536, 256, 0, stream>>>(Wqkv, Wqkv16);
        cvt_f32_bf16<<< 512, 256, 0, stream>>>(Wproj, Wproj16);

        lora_xa_kernel<bf16_t><<<2048, 256, 0, stream>>>(x16, Aqkv, xa1);

        gemm_async<<<dim3(24, 64), 256, 0, stream>>>(
            x16, Wqkv16, bqkv, xa1, Bqkv, Qfull, Kfull, Vfull, nullptr, 1024);

        attn_kernel<<<2048, 256, 0, stream>>>(Qfull, Kfull, Vfull);

        lora_xa_kernel<bf16_t><<<2048, 256, 0, stream>>>(Qfull, Aproj, xa2);

        gemm_async<<<dim3(8, 64), 256, 0, stream>>>(
            Qfull, Wproj16, bproj, xa2, Bproj,
            nullptr, nullptr, nullptr, out, 1024);
    } else {
        // fallback (proven 48.5 MiB layout, round-6 structure)
        float*  xa1   = (float*)ws;
        float*  xa2   = (float*)(ws + 262144);
        bf16_t* Qfull = (bf16_t*)(ws + 524288);
        bf16_t* Kfull = Qfull + (size_t)8192 * 1024;
        bf16_t* Vfull = Kfull + (size_t)8192 * 1024;

        lora_xa_kernel<float><<<2048, 256, 0, stream>>>(x, Aqkv, xa1);
        gemm_bias_lora<float, float><<<dim3(24, 64), 256, 0, stream>>>(
            x, Wqkv, bqkv, xa1, Bqkv, Qfull, Kfull, Vfull, nullptr, 1024);
        attn_kernel<<<2048, 256, 0, stream>>>(Qfull, Kfull, Vfull);
        lora_xa_kernel<bf16_t><<<2048, 256, 0, stream>>>(Qfull, Aproj, xa2);
        gemm_bias_lora<bf16_t, float><<<dim3(8, 64), 256, 0, stream>>>(
            Qfull, Wproj, bproj, xa2, Bproj,
            nullptr, nullptr, nullptr, out, 1024);
    }
    (void)MB;
}